// Round 2
// baseline (5824.574 us; speedup 1.0000x reference)
//
#include <hip/hip_runtime.h>
#include <hip/hip_cooperative_groups.h>
#include <math.h>

namespace cg = cooperative_groups;

#define Bsz 64
#define Pp  196
#define ENC 2048
#define Ee  512
#define Hh  512
#define Vv  10000
#define Tt  20
#define H4  2048

typedef short bf16x8 __attribute__((ext_vector_type(8)));
typedef float f32x4 __attribute__((ext_vector_type(4)));

__device__ __forceinline__ float sigmoidf_(float x) { return 1.0f / (1.0f + expf(-x)); }

__device__ __forceinline__ unsigned short bf16r(float x) {
    union { float f; unsigned int u; } c; c.f = x;
    unsigned int lsb = (c.u >> 16) & 1u;
    return (unsigned short)((c.u + 0x7fffu + lsb) >> 16);
}

// ---------------- v_enc[e] = sum_a W_full[a] * W_enc[a][e] ----------------
__global__ __launch_bounds__(256) void k_venc(const float* __restrict__ W_full,
                                              const float* __restrict__ W_enc,
                                              float* __restrict__ v_enc) {
    int lane = threadIdx.x & 63, ag = threadIdx.x >> 6;
    int e = blockIdx.x * 64 + lane;
    float s = 0.f;
    #pragma unroll 8
    for (int a = ag * 128; a < ag * 128 + 128; ++a)
        s += W_full[a] * W_enc[(size_t)a * ENC + e];
    __shared__ float red[4][64];
    red[ag][lane] = s;
    __syncthreads();
    if (threadIdx.x < 64)
        v_enc[e] = red[0][lane] + red[1][lane] + red[2][lane] + red[3][lane];
}

// ---------------- scores: sc[b][p] = dot(img[b][p], v_enc) ----------------
__global__ __launch_bounds__(256) void k_scores(const float* __restrict__ img,
                                                const float* __restrict__ v_enc,
                                                float* __restrict__ sc) {
    int b = blockIdx.y;
    int wave = threadIdx.x >> 6, lane = threadIdx.x & 63;
    int p = blockIdx.x * 4 + wave;
    __shared__ float4 sv[ENC / 4];
    const float4* ve4 = (const float4*)v_enc;
    sv[threadIdx.x] = ve4[threadIdx.x];
    sv[threadIdx.x + 256] = ve4[threadIdx.x + 256];
    __syncthreads();
    const float4* row = (const float4*)(img + ((size_t)b * Pp + p) * ENC);
    float s = 0.f;
    #pragma unroll
    for (int it = 0; it < 8; ++it) {
        int idx = it * 64 + lane;
        float4 v = row[idx];
        float4 w = sv[idx];
        s += v.x * w.x + v.y * w.y + v.z * w.z + v.w * w.w;
    }
    #pragma unroll
    for (int off = 32; off > 0; off >>= 1) s += __shfl_down(s, off);
    if (lane == 0) sc[b * Pp + p] = s;
}

// ---------------- softmax over p; writes alpha + broadcast alphas_out ----------------
__global__ __launch_bounds__(256) void k_softmax(const float* __restrict__ sc,
                                                 float* __restrict__ alpha,
                                                 float* __restrict__ alphas_out) {
    int b = blockIdx.x, tid = threadIdx.x;
    __shared__ float red[256];
    __shared__ float sa[Pp];
    float v = (tid < Pp) ? sc[b * Pp + tid] : -INFINITY;
    red[tid] = v; __syncthreads();
    for (int off = 128; off > 0; off >>= 1) {
        if (tid < off) red[tid] = fmaxf(red[tid], red[tid + off]);
        __syncthreads();
    }
    float mx = red[0]; __syncthreads();
    float ex = (tid < Pp) ? expf(v - mx) : 0.f;
    red[tid] = ex; __syncthreads();
    for (int off = 128; off > 0; off >>= 1) {
        if (tid < off) red[tid] += red[tid + off];
        __syncthreads();
    }
    float inv = 1.f / red[0];
    if (tid < Pp) { sa[tid] = ex * inv; alpha[b * Pp + tid] = ex * inv; }
    __syncthreads();
    for (int i = tid; i < Tt * Pp; i += 256)
        alphas_out[(size_t)b * Tt * Pp + i] = sa[i % Pp];
}

// ---------------- context + avg ----------------
__global__ __launch_bounds__(256) void k_ctx(const float* __restrict__ img,
                                             const float* __restrict__ alpha,
                                             float* __restrict__ context,
                                             float* __restrict__ avg) {
    int b = blockIdx.y;
    int e2 = blockIdx.x * 256 + threadIdx.x;
    __shared__ float sa[Pp];
    if (threadIdx.x < Pp) sa[threadIdx.x] = alpha[b * Pp + threadIdx.x];
    __syncthreads();
    const float2* ib2 = (const float2*)(img + (size_t)b * Pp * ENC);
    float cx = 0.f, cy = 0.f, ax = 0.f, ay = 0.f;
    for (int p = 0; p < Pp; p += 4) {
        #pragma unroll
        for (int q = 0; q < 4; ++q) {
            float ap = sa[p + q];
            float2 v = ib2[(size_t)(p + q) * (ENC / 2) + e2];
            cx += ap * v.x; cy += ap * v.y;
            ax += v.x;      ay += v.y;
        }
    }
    float2* c2 = (float2*)(context + (size_t)b * ENC);
    float2* a2 = (float2*)(avg + (size_t)b * ENC);
    c2[e2] = make_float2(cx, cy);
    a2[e2] = make_float2(ax * (1.f / 196.f), ay * (1.f / 196.f));
}

// ---------------- init GEMM: h0|c0 = avg @ [Winit_h | Winit_c]^T + bias ----------------
// BM=64, BN=16, BK=64, TM=4. grid 64 blocks (N=1024).
__global__ __launch_bounds__(256) void gemm_init(
    const float* __restrict__ A,
    const float* __restrict__ B0, const float* __restrict__ B1,
    float* __restrict__ h0, float* __restrict__ cbuf,
    const float* __restrict__ bias0, const float* __restrict__ bias1) {
    const int tid = threadIdx.x;
    const int tx = tid & 15, ty = tid >> 4;
    const int n0 = blockIdx.x * 16;

    const float* Brow = (n0 < 512) ? B0 + (size_t)n0 * ENC : B1 + (size_t)(n0 - 512) * ENC;

    __shared__ float As[64][68];
    __shared__ float Bs[64][20];

    float4 pa[4], pb;
    const int sm[4] = { tid >> 4, (256 + tid) >> 4, (512 + tid) >> 4, (768 + tid) >> 4 };
    const int scc = tid & 15;
    const int bn = tid >> 4, bc = tid & 15;

    auto load_chunk = [&](int c) {
        int k0 = c * 64;
        #pragma unroll
        for (int i = 0; i < 4; ++i)
            pa[i] = *(const float4*)(A + (size_t)sm[i] * ENC + k0 + 4 * scc);
        pb = *(const float4*)(Brow + (size_t)bn * ENC + k0 + 4 * bc);
    };

    float acc[4] = {};
    load_chunk(0);
    for (int c = 0; c < 32; ++c) {
        __syncthreads();
        #pragma unroll
        for (int i = 0; i < 4; ++i) {
            As[4 * scc + 0][sm[i]] = pa[i].x;
            As[4 * scc + 1][sm[i]] = pa[i].y;
            As[4 * scc + 2][sm[i]] = pa[i].z;
            As[4 * scc + 3][sm[i]] = pa[i].w;
        }
        Bs[4 * bc + 0][bn] = pb.x;
        Bs[4 * bc + 1][bn] = pb.y;
        Bs[4 * bc + 2][bn] = pb.z;
        Bs[4 * bc + 3][bn] = pb.w;
        __syncthreads();
        if (c + 1 < 32) load_chunk(c + 1);
        #pragma unroll 8
        for (int kk = 0; kk < 64; ++kk) {
            float4 a = *(const float4*)&As[kk][ty * 4];
            float bb = Bs[kk][tx];
            acc[0] += a.x * bb; acc[1] += a.y * bb;
            acc[2] += a.z * bb; acc[3] += a.w * bb;
        }
    }

    int gn = n0 + tx;
    #pragma unroll
    for (int i = 0; i < 4; ++i) {
        int m = ty * 4 + i;
        if (gn < 512) h0[(size_t)m * 512 + gn]           = acc[i] + bias0[gn];
        else          cbuf[(size_t)m * 512 + (gn - 512)] = acc[i] + bias1[gn - 512];
    }
}

// ---------------- emb GEMM with fused gather: BM=128, BN=64, BK=32 ----------------
__global__ __launch_bounds__(256) void gemm_emb(const int* __restrict__ captions,
                                                const float* __restrict__ emb,
                                                const float* __restrict__ Bm,
                                                float* __restrict__ C,
                                                const float* __restrict__ bias,
                                                const float* __restrict__ bias2) {
    const int tid = threadIdx.x;
    const int tx = tid & 15, ty = tid >> 4;
    const int m0 = blockIdx.y * 128, n0 = blockIdx.x * 64;

    __shared__ float As[32][132];
    __shared__ float Bs[32][68];

    float4 pa[4], pb[2];
    const int am[4] = { tid >> 3, (256 + tid) >> 3, (512 + tid) >> 3, (768 + tid) >> 3 };
    const int ac = tid & 7;
    const int bnr[2] = { tid >> 3, (256 + tid) >> 3 };
    const int bc = tid & 7;

    const float* arow[4];
    #pragma unroll
    for (int i = 0; i < 4; ++i) {
        int r = m0 + am[i];
        arow[i] = emb + (size_t)captions[(r & 63) * Tt + (r >> 6)] * Ee;
    }

    const int nchunk = Ee / 32;
    auto load_chunk = [&](int c) {
        int k0 = c * 32;
        #pragma unroll
        for (int i = 0; i < 4; ++i)
            pa[i] = *(const float4*)(arow[i] + k0 + 4 * ac);
        #pragma unroll
        for (int i = 0; i < 2; ++i)
            pb[i] = *(const float4*)(Bm + (size_t)(n0 + bnr[i]) * 2560 + k0 + 4 * bc);
    };

    float acc[8][4] = {};
    load_chunk(0);
    for (int c = 0; c < nchunk; ++c) {
        __syncthreads();
        #pragma unroll
        for (int i = 0; i < 4; ++i) {
            As[4 * ac + 0][am[i]] = pa[i].x;
            As[4 * ac + 1][am[i]] = pa[i].y;
            As[4 * ac + 2][am[i]] = pa[i].z;
            As[4 * ac + 3][am[i]] = pa[i].w;
        }
        #pragma unroll
        for (int i = 0; i < 2; ++i) {
            Bs[4 * bc + 0][bnr[i]] = pb[i].x;
            Bs[4 * bc + 1][bnr[i]] = pb[i].y;
            Bs[4 * bc + 2][bnr[i]] = pb[i].z;
            Bs[4 * bc + 3][bnr[i]] = pb[i].w;
        }
        __syncthreads();
        if (c + 1 < nchunk) load_chunk(c + 1);
        #pragma unroll 4
        for (int kk = 0; kk < 32; ++kk) {
            float4 a0 = *(const float4*)&As[kk][ty * 8];
            float4 a1 = *(const float4*)&As[kk][ty * 8 + 4];
            float4 b0 = *(const float4*)&Bs[kk][tx * 4];
            float av[8] = { a0.x, a0.y, a0.z, a0.w, a1.x, a1.y, a1.z, a1.w };
            float bv[4] = { b0.x, b0.y, b0.z, b0.w };
            #pragma unroll
            for (int i = 0; i < 8; ++i)
                #pragma unroll
                for (int j = 0; j < 4; ++j)
                    acc[i][j] += av[i] * bv[j];
        }
    }

    #pragma unroll
    for (int i = 0; i < 8; ++i) {
        int m = m0 + ty * 8 + i;
        #pragma unroll
        for (int j = 0; j < 4; ++j) {
            int gn = n0 + tx * 4 + j;
            C[(size_t)m * H4 + gn] = acc[i][j] + bias[gn] + bias2[gn];
        }
    }
}

// ---------------- persistent cooperative recurrence ----------------
// 256 blocks x 512 threads; block (bg = bid&3, cgp = bid>>2).
// Stage A: gc[b][n] = sigmoid(h . W_beta[n] + b_beta[n]) * ctx[b][n]
//          b in [bg*16, +16), n in [cgp*32, +32); 1 output/thread.
// Stage B: gate pre-act v[b][G], G = gidx*512 + (cgp*8 + jl); K = 2048 (gc) + 512 (h).
//          LSTM fused via __shfl gate exchange; writes h (double-buffered), c, H_bf16
//          with H rows in (b*20 + t) order for the preds GEMM.
__global__ __launch_bounds__(512) void k_loop(
    const float* __restrict__ W_beta, const float* __restrict__ b_beta,
    const float* __restrict__ W_ih,   const float* __restrict__ W_hh,
    const float* __restrict__ context, const float* __restrict__ emb_part,
    float* __restrict__ h0, float* __restrict__ h1,
    float* __restrict__ cbuf, float* __restrict__ gc,
    unsigned short* __restrict__ Hbf) {
    cg::grid_group grid = cg::this_grid();
    const int tid = threadIdx.x;
    const int bid = blockIdx.x;
    const int cgp = bid >> 2;            // 0..63
    const int bg  = bid & 3;             // 0..3
    const int local = tid & 31;
    const int b = bg * 16 + (tid >> 5);  // 0..63

    const int nA = cgp * 32 + local;
    const float bbeta = b_beta[nA];
    const float* wbrow = W_beta + (size_t)nA * 512;

    const int gidx = local >> 3, jl = local & 7;
    const int jB = cgp * 8 + jl;
    const int G = gidx * 512 + jB;
    const float* wgrow = W_ih + (size_t)G * 2560 + 512;
    const float* whrow = W_hh + (size_t)G * 512;

    float* hs[2] = { h0, h1 };

    for (int t = 0; t < Tt; ++t) {
        const float* h = hs[t & 1];
        float* hn = hs[(t + 1) & 1];

        // ---- stage A ----
        {
            const float4* hr = (const float4*)(h + (size_t)b * 512);
            const float4* wr = (const float4*)wbrow;
            float a0 = 0.f, a1 = 0.f, a2 = 0.f, a3 = 0.f;
            #pragma unroll 8
            for (int k = 0; k < 128; ++k) {
                float4 hv = hr[k], wv = wr[k];
                a0 += hv.x * wv.x; a1 += hv.y * wv.y;
                a2 += hv.z * wv.z; a3 += hv.w * wv.w;
            }
            float s = sigmoidf_((a0 + a1) + (a2 + a3) + bbeta);
            gc[(size_t)b * 2048 + nA] = s * context[(size_t)b * 2048 + nA];
        }
        grid.sync();

        // ---- stage B ----
        {
            const float4* gr = (const float4*)(gc + (size_t)b * 2048);
            const float4* wr = (const float4*)wgrow;
            float a0 = 0.f, a1 = 0.f, a2 = 0.f, a3 = 0.f;
            #pragma unroll 8
            for (int k = 0; k < 512; ++k) {
                float4 g = gr[k], w = wr[k];
                a0 += g.x * w.x; a1 += g.y * w.y;
                a2 += g.z * w.z; a3 += g.w * w.w;
            }
            const float4* hr = (const float4*)(h + (size_t)b * 512);
            const float4* wh = (const float4*)whrow;
            #pragma unroll 8
            for (int k = 0; k < 128; ++k) {
                float4 hv = hr[k], w = wh[k];
                a0 += hv.x * w.x; a1 += hv.y * w.y;
                a2 += hv.z * w.z; a3 += hv.w * w.w;
            }
            float v = (a0 + a1) + (a2 + a3)
                    + emb_part[((size_t)t * 64 + b) * 2048 + G];
            int lane = tid & 63;
            float vf = __shfl(v, lane + 8);
            float vg = __shfl(v, lane + 16);
            float vo = __shfl(v, lane + 24);
            if (gidx == 0) {
                float i_ = sigmoidf_(v);
                float f_ = sigmoidf_(vf);
                float g_ = tanhf(vg);
                float o_ = sigmoidf_(vo);
                size_t ci = (size_t)b * 512 + jB;
                float cn = f_ * cbuf[ci] + i_ * g_;
                float hv2 = o_ * tanhf(cn);
                cbuf[ci] = cn;
                hn[ci] = hv2;
                Hbf[((size_t)b * Tt + t) * 512 + jB] = bf16r(hv2);
            }
        }
        grid.sync();
    }
}

// ---------------- W_out fp32 -> bf16 ----------------
__global__ __launch_bounds__(256) void k_cvt(const float* __restrict__ src,
                                             unsigned short* __restrict__ dst) {
    int i = blockIdx.x * 256 + threadIdx.x;
    if (i >= (Vv * Hh) / 4) return;
    float4 v = ((const float4*)src)[i];
    ushort4 o;
    o.x = bf16r(v.x); o.y = bf16r(v.y); o.z = bf16r(v.z); o.w = bf16r(v.w);
    ((ushort4*)dst)[i] = o;
}

// ---------------- preds: bf16 MFMA GEMM, 128x128 tile, BK=32 ----------------
// H rows already in (b*20+t) order -> direct, contiguous C writes.
// grid (10 m-blocks, 79 n-blocks): consecutive blocks share the B-tile.
__global__ __launch_bounds__(256) void gemm_preds(const unsigned short* __restrict__ Hb,
                                                  const unsigned short* __restrict__ Wb,
                                                  const float* __restrict__ b_out,
                                                  float* __restrict__ preds) {
    const int tid = threadIdx.x;
    const int lane = tid & 63, wave = tid >> 6;
    const int wr = wave >> 1, wc = wave & 1;
    const int m0 = blockIdx.x * 128, n0 = blockIdx.y * 128;

    __shared__ unsigned short As[128][40];
    __shared__ unsigned short Bs[128][40];

    const int r0 = tid >> 2, c8 = (tid & 3) * 8;
    uint4 pa[2], pb[2];
    auto load = [&](int c) {
        int k0 = c * 32;
        #pragma unroll
        for (int i = 0; i < 2; ++i) {
            int r = r0 + i * 64;
            pa[i] = *(const uint4*)(Hb + (size_t)(m0 + r) * 512 + k0 + c8);
            int gn = n0 + r; gn = (gn > Vv - 1) ? (Vv - 1) : gn;
            pb[i] = *(const uint4*)(Wb + (size_t)gn * 512 + k0 + c8);
        }
    };

    union F8 { bf16x8 v; struct { unsigned long long lo, hi; } u; };
    f32x4 acc[4][4] = {};

    const int arow = wr * 64 + (lane & 15);
    const int brow = wc * 64 + (lane & 15);
    const int kg = (lane >> 4) * 4;

    load(0);
    for (int c = 0; c < 16; ++c) {
        __syncthreads();
        #pragma unroll
        for (int i = 0; i < 2; ++i) {
            *(uint4*)&As[r0 + i * 64][c8] = pa[i];
            *(uint4*)&Bs[r0 + i * 64][c8] = pb[i];
        }
        __syncthreads();
        if (c < 15) load(c + 1);
        F8 af[4], bfr[4];
        #pragma unroll
        for (int x = 0; x < 4; ++x) {
            af[x].u.lo  = *(const unsigned long long*)&As[arow + x * 16][kg];
            af[x].u.hi  = *(const unsigned long long*)&As[arow + x * 16][16 + kg];
            bfr[x].u.lo = *(const unsigned long long*)&Bs[brow + x * 16][kg];
            bfr[x].u.hi = *(const unsigned long long*)&Bs[brow + x * 16][16 + kg];
        }
        #pragma unroll
        for (int mi = 0; mi < 4; ++mi)
            #pragma unroll
            for (int ni = 0; ni < 4; ++ni)
                acc[mi][ni] = __builtin_amdgcn_mfma_f32_16x16x32_bf16(
                    af[mi].v, bfr[ni].v, acc[mi][ni], 0, 0, 0);
    }

    const int crow = (lane >> 4) * 4, ccol = lane & 15;
    #pragma unroll
    for (int mi = 0; mi < 4; ++mi) {
        #pragma unroll
        for (int ni = 0; ni < 4; ++ni) {
            int n = n0 + wc * 64 + ni * 16 + ccol;
            if (n >= Vv) continue;
            float bo = b_out[n];
            #pragma unroll
            for (int r = 0; r < 4; ++r) {
                int m = m0 + wr * 64 + mi * 16 + crow + r;
                preds[(size_t)m * Vv + n] = acc[mi][ni][r] + bo;
            }
        }
    }
}

extern "C" void kernel_launch(void* const* d_in, const int* in_sizes, int n_in,
                              void* d_out, int out_size, void* d_ws, size_t ws_size,
                              hipStream_t stream) {
    const float* img_feat  = (const float*)d_in[0];
    const int*   captions  = (const int*)d_in[1];
    const float* embedding = (const float*)d_in[2];
    const float* W_enc_att = (const float*)d_in[3];
    const float* W_full    = (const float*)d_in[7];
    const float* W_beta    = (const float*)d_in[9];
    const float* b_beta    = (const float*)d_in[10];
    const float* W_ih      = (const float*)d_in[11];
    const float* b_ih      = (const float*)d_in[12];
    const float* W_hh      = (const float*)d_in[13];
    const float* b_hh      = (const float*)d_in[14];
    const float* W_init_h  = (const float*)d_in[15];
    const float* b_init_h  = (const float*)d_in[16];
    const float* W_init_c  = (const float*)d_in[17];
    const float* b_init_c  = (const float*)d_in[18];
    const float* W_out     = (const float*)d_in[19];
    const float* b_out     = (const float*)d_in[20];

    float* preds_out  = (float*)d_out;
    float* alphas_out = (float*)d_out + (size_t)Bsz * Tt * Vv;

    float* ws = (float*)d_ws;
    float* v_enc    = ws;                         // 2048
    float* sc       = v_enc + ENC;                // 12544
    float* alpha    = sc + Bsz * Pp;              // 12544
    float* context  = alpha + Bsz * Pp;           // 131072
    float* avg      = context + Bsz * ENC;        // 131072
    float* h0buf    = avg + Bsz * ENC;            // 32768
    float* h1buf    = h0buf + Bsz * Hh;           // 32768
    float* cbuf     = h1buf + Bsz * Hh;           // 32768
    float* gc       = cbuf + Bsz * Hh;            // 131072
    float* emb_part = gc + Bsz * ENC;             // 1280*2048
    unsigned short* H_bf16 = (unsigned short*)(emb_part + (size_t)Tt * Bsz * H4); // 1280*512
    unsigned short* Wout_bf16 = (unsigned short*)emb_part; // alias: used only after loop

    // attention (timestep-invariant)
    k_venc<<<32, 256, 0, stream>>>(W_full, W_enc_att, v_enc);
    k_scores<<<dim3(49, 64), 256, 0, stream>>>(img_feat, v_enc, sc);
    k_softmax<<<64, 256, 0, stream>>>(sc, alpha, alphas_out);
    k_ctx<<<dim3(4, 64), 256, 0, stream>>>(img_feat, alpha, context, avg);

    // h0 / c0 init
    gemm_init<<<64, 256, 0, stream>>>(
        avg, W_init_h, W_init_c, h0buf, cbuf, b_init_h, b_init_c);

    // embedding part of gates for all steps (gather fused)
    gemm_emb<<<dim3(H4 / 64, (Tt * Bsz) / 128), 256, 0, stream>>>(
        captions, embedding, W_ih, emb_part, b_ih, b_hh);

    // persistent cooperative recurrence (all 20 steps)
    {
        const float* a0 = W_beta;  const float* a1 = b_beta;
        const float* a2 = W_ih;    const float* a3 = W_hh;
        const float* a4 = context; const float* a5 = emb_part;
        float* a6 = h0buf; float* a7 = h1buf;
        float* a8 = cbuf;  float* a9 = gc;
        unsigned short* a10 = H_bf16;
        void* args[] = { &a0, &a1, &a2, &a3, &a4, &a5, &a6, &a7, &a8, &a9, &a10 };
        hipLaunchCooperativeKernel((const void*)k_loop, dim3(256), dim3(512),
                                   args, 0, stream);
    }

    // W_out -> bf16 (emb_part dead after loop)
    k_cvt<<<(Vv * Hh / 4 + 255) / 256, 256, 0, stream>>>(W_out, Wout_bf16);

    // preds via bf16 MFMA (H rows already in b*20+t order)
    gemm_preds<<<dim3((Tt * Bsz) / 128, (Vv + 127) / 128), 256, 0, stream>>>(
        H_bf16, Wout_bf16, b_out, preds_out);
}

// Round 3
// 1936.642 us; speedup vs baseline: 3.0076x; 3.0076x over previous
//
#include <hip/hip_runtime.h>
#include <math.h>

#define Bsz 64
#define Pp  196
#define ENC 2048
#define Ee  512
#define Hh  512
#define Vv  10000
#define Tt  20
#define H4  2048

typedef short bf16x8 __attribute__((ext_vector_type(8)));
typedef float f32x4 __attribute__((ext_vector_type(4)));

__device__ __forceinline__ float sigmoidf_(float x) { return 1.0f / (1.0f + expf(-x)); }

__device__ __forceinline__ unsigned short bf16r(float x) {
    union { float f; unsigned int u; } c; c.f = x;
    unsigned int lsb = (c.u >> 16) & 1u;
    return (unsigned short)((c.u + 0x7fffu + lsb) >> 16);
}

// ---------------- v_enc[e] = sum_a W_full[a] * W_enc[a][e] ----------------
__global__ __launch_bounds__(256) void k_venc(const float* __restrict__ W_full,
                                              const float* __restrict__ W_enc,
                                              float* __restrict__ v_enc) {
    int lane = threadIdx.x & 63, ag = threadIdx.x >> 6;
    int e = blockIdx.x * 64 + lane;
    float s = 0.f;
    #pragma unroll 8
    for (int a = ag * 128; a < ag * 128 + 128; ++a)
        s += W_full[a] * W_enc[(size_t)a * ENC + e];
    __shared__ float red[4][64];
    red[ag][lane] = s;
    __syncthreads();
    if (threadIdx.x < 64)
        v_enc[e] = red[0][lane] + red[1][lane] + red[2][lane] + red[3][lane];
}

// ---------------- scores: sc[b][p] = dot(img[b][p], v_enc) ----------------
__global__ __launch_bounds__(256) void k_scores(const float* __restrict__ img,
                                                const float* __restrict__ v_enc,
                                                float* __restrict__ sc) {
    int b = blockIdx.y;
    int wave = threadIdx.x >> 6, lane = threadIdx.x & 63;
    int p = blockIdx.x * 4 + wave;
    __shared__ float4 sv[ENC / 4];
    const float4* ve4 = (const float4*)v_enc;
    sv[threadIdx.x] = ve4[threadIdx.x];
    sv[threadIdx.x + 256] = ve4[threadIdx.x + 256];
    __syncthreads();
    const float4* row = (const float4*)(img + ((size_t)b * Pp + p) * ENC);
    float s = 0.f;
    #pragma unroll
    for (int it = 0; it < 8; ++it) {
        int idx = it * 64 + lane;
        float4 v = row[idx];
        float4 w = sv[idx];
        s += v.x * w.x + v.y * w.y + v.z * w.z + v.w * w.w;
    }
    #pragma unroll
    for (int off = 32; off > 0; off >>= 1) s += __shfl_down(s, off);
    if (lane == 0) sc[b * Pp + p] = s;
}

// ---------------- softmax over p; writes alpha + broadcast alphas_out ----------------
__global__ __launch_bounds__(256) void k_softmax(const float* __restrict__ sc,
                                                 float* __restrict__ alpha,
                                                 float* __restrict__ alphas_out) {
    int b = blockIdx.x, tid = threadIdx.x;
    __shared__ float red[256];
    __shared__ float sa[Pp];
    float v = (tid < Pp) ? sc[b * Pp + tid] : -INFINITY;
    red[tid] = v; __syncthreads();
    for (int off = 128; off > 0; off >>= 1) {
        if (tid < off) red[tid] = fmaxf(red[tid], red[tid + off]);
        __syncthreads();
    }
    float mx = red[0]; __syncthreads();
    float ex = (tid < Pp) ? expf(v - mx) : 0.f;
    red[tid] = ex; __syncthreads();
    for (int off = 128; off > 0; off >>= 1) {
        if (tid < off) red[tid] += red[tid + off];
        __syncthreads();
    }
    float inv = 1.f / red[0];
    if (tid < Pp) { sa[tid] = ex * inv; alpha[b * Pp + tid] = ex * inv; }
    __syncthreads();
    for (int i = tid; i < Tt * Pp; i += 256)
        alphas_out[(size_t)b * Tt * Pp + i] = sa[i % Pp];
}

// ---------------- context + avg ----------------
__global__ __launch_bounds__(256) void k_ctx(const float* __restrict__ img,
                                             const float* __restrict__ alpha,
                                             float* __restrict__ context,
                                             float* __restrict__ avg) {
    int b = blockIdx.y;
    int e2 = blockIdx.x * 256 + threadIdx.x;
    __shared__ float sa[Pp];
    if (threadIdx.x < Pp) sa[threadIdx.x] = alpha[b * Pp + threadIdx.x];
    __syncthreads();
    const float2* ib2 = (const float2*)(img + (size_t)b * Pp * ENC);
    float cx = 0.f, cy = 0.f, ax = 0.f, ay = 0.f;
    for (int p = 0; p < Pp; p += 4) {
        #pragma unroll
        for (int q = 0; q < 4; ++q) {
            float ap = sa[p + q];
            float2 v = ib2[(size_t)(p + q) * (ENC / 2) + e2];
            cx += ap * v.x; cy += ap * v.y;
            ax += v.x;      ay += v.y;
        }
    }
    float2* c2 = (float2*)(context + (size_t)b * ENC);
    float2* a2 = (float2*)(avg + (size_t)b * ENC);
    c2[e2] = make_float2(cx, cy);
    a2[e2] = make_float2(ax * (1.f / 196.f), ay * (1.f / 196.f));
}

// ---------------- init GEMM: h0|c0 = avg @ [Winit_h | Winit_c]^T + bias ----------------
__global__ __launch_bounds__(256) void gemm_init(
    const float* __restrict__ A,
    const float* __restrict__ B0, const float* __restrict__ B1,
    float* __restrict__ h0, float* __restrict__ cbuf,
    const float* __restrict__ bias0, const float* __restrict__ bias1) {
    const int tid = threadIdx.x;
    const int tx = tid & 15, ty = tid >> 4;
    const int n0 = blockIdx.x * 16;

    const float* Brow = (n0 < 512) ? B0 + (size_t)n0 * ENC : B1 + (size_t)(n0 - 512) * ENC;

    __shared__ float As[64][68];
    __shared__ float Bs[64][20];

    float4 pa[4], pb;
    const int sm[4] = { tid >> 4, (256 + tid) >> 4, (512 + tid) >> 4, (768 + tid) >> 4 };
    const int scc = tid & 15;
    const int bn = tid >> 4, bc = tid & 15;

    auto load_chunk = [&](int c) {
        int k0 = c * 64;
        #pragma unroll
        for (int i = 0; i < 4; ++i)
            pa[i] = *(const float4*)(A + (size_t)sm[i] * ENC + k0 + 4 * scc);
        pb = *(const float4*)(Brow + (size_t)bn * ENC + k0 + 4 * bc);
    };

    float acc[4] = {};
    load_chunk(0);
    for (int c = 0; c < 32; ++c) {
        __syncthreads();
        #pragma unroll
        for (int i = 0; i < 4; ++i) {
            As[4 * scc + 0][sm[i]] = pa[i].x;
            As[4 * scc + 1][sm[i]] = pa[i].y;
            As[4 * scc + 2][sm[i]] = pa[i].z;
            As[4 * scc + 3][sm[i]] = pa[i].w;
        }
        Bs[4 * bc + 0][bn] = pb.x;
        Bs[4 * bc + 1][bn] = pb.y;
        Bs[4 * bc + 2][bn] = pb.z;
        Bs[4 * bc + 3][bn] = pb.w;
        __syncthreads();
        if (c + 1 < 32) load_chunk(c + 1);
        #pragma unroll 8
        for (int kk = 0; kk < 64; ++kk) {
            float4 a = *(const float4*)&As[kk][ty * 4];
            float bb = Bs[kk][tx];
            acc[0] += a.x * bb; acc[1] += a.y * bb;
            acc[2] += a.z * bb; acc[3] += a.w * bb;
        }
    }

    int gn = n0 + tx;
    #pragma unroll
    for (int i = 0; i < 4; ++i) {
        int m = ty * 4 + i;
        if (gn < 512) h0[(size_t)m * 512 + gn]           = acc[i] + bias0[gn];
        else          cbuf[(size_t)m * 512 + (gn - 512)] = acc[i] + bias1[gn - 512];
    }
}

// ---------------- emb GEMM with fused gather: BM=128, BN=64, BK=32 ----------------
__global__ __launch_bounds__(256) void gemm_emb(const int* __restrict__ captions,
                                                const float* __restrict__ emb,
                                                const float* __restrict__ Bm,
                                                float* __restrict__ C,
                                                const float* __restrict__ bias,
                                                const float* __restrict__ bias2) {
    const int tid = threadIdx.x;
    const int tx = tid & 15, ty = tid >> 4;
    const int m0 = blockIdx.y * 128, n0 = blockIdx.x * 64;

    __shared__ float As[32][132];
    __shared__ float Bs[32][68];

    float4 pa[4], pb[2];
    const int am[4] = { tid >> 3, (256 + tid) >> 3, (512 + tid) >> 3, (768 + tid) >> 3 };
    const int ac = tid & 7;
    const int bnr[2] = { tid >> 3, (256 + tid) >> 3 };
    const int bc = tid & 7;

    const float* arow[4];
    #pragma unroll
    for (int i = 0; i < 4; ++i) {
        int r = m0 + am[i];
        arow[i] = emb + (size_t)captions[(r & 63) * Tt + (r >> 6)] * Ee;
    }

    const int nchunk = Ee / 32;
    auto load_chunk = [&](int c) {
        int k0 = c * 32;
        #pragma unroll
        for (int i = 0; i < 4; ++i)
            pa[i] = *(const float4*)(arow[i] + k0 + 4 * ac);
        #pragma unroll
        for (int i = 0; i < 2; ++i)
            pb[i] = *(const float4*)(Bm + (size_t)(n0 + bnr[i]) * 2560 + k0 + 4 * bc);
    };

    float acc[8][4] = {};
    load_chunk(0);
    for (int c = 0; c < nchunk; ++c) {
        __syncthreads();
        #pragma unroll
        for (int i = 0; i < 4; ++i) {
            As[4 * ac + 0][am[i]] = pa[i].x;
            As[4 * ac + 1][am[i]] = pa[i].y;
            As[4 * ac + 2][am[i]] = pa[i].z;
            As[4 * ac + 3][am[i]] = pa[i].w;
        }
        #pragma unroll
        for (int i = 0; i < 2; ++i) {
            Bs[4 * bc + 0][bnr[i]] = pb[i].x;
            Bs[4 * bc + 1][bnr[i]] = pb[i].y;
            Bs[4 * bc + 2][bnr[i]] = pb[i].z;
            Bs[4 * bc + 3][bnr[i]] = pb[i].w;
        }
        __syncthreads();
        if (c + 1 < nchunk) load_chunk(c + 1);
        #pragma unroll 4
        for (int kk = 0; kk < 32; ++kk) {
            float4 a0 = *(const float4*)&As[kk][ty * 8];
            float4 a1 = *(const float4*)&As[kk][ty * 8 + 4];
            float4 b0 = *(const float4*)&Bs[kk][tx * 4];
            float av[8] = { a0.x, a0.y, a0.z, a0.w, a1.x, a1.y, a1.z, a1.w };
            float bv[4] = { b0.x, b0.y, b0.z, b0.w };
            #pragma unroll
            for (int i = 0; i < 8; ++i)
                #pragma unroll
                for (int j = 0; j < 4; ++j)
                    acc[i][j] += av[i] * bv[j];
        }
    }

    #pragma unroll
    for (int i = 0; i < 8; ++i) {
        int m = m0 + ty * 8 + i;
        #pragma unroll
        for (int j = 0; j < 4; ++j) {
            int gn = n0 + tx * 4 + j;
            C[(size_t)m * H4 + gn] = acc[i][j] + bias[gn] + bias2[gn];
        }
    }
}

// ---------------- step kernel 1: h -> gc and P0 ----------------
// grid (256, 4); block 256 thr = 16 n x 16 b. N=4096: n<2048 -> gc (sigmoid*ctx),
// n>=2048 -> P0 = h @ W_hh^T (raw preact). K=512. Weights LDS-staged, broadcast reads.
__global__ __launch_bounds__(256) void k_g1(
    const float* __restrict__ W_beta, const float* __restrict__ b_beta,
    const float* __restrict__ W_hh,
    const float* __restrict__ h, const float* __restrict__ context,
    float* __restrict__ gc, float* __restrict__ P0) {
    const int tid = threadIdx.x;
    const int tx = tid & 15, ty = tid >> 4;
    const int n0 = blockIdx.x * 16;
    const int b  = blockIdx.y * 16 + ty;

    __shared__ float Ws[16 * 516];   // row stride 516: banks (4r+4i)%32 -> 2-way max

    #pragma unroll
    for (int i = 0; i < 8; ++i) {
        int f = tid + i * 256;              // float4 index < 2048
        int r = f >> 7, c = (f & 127) * 4;
        int n = n0 + r;
        const float* src = (n < 2048) ? (W_beta + (size_t)n * 512)
                                      : (W_hh + (size_t)(n - 2048) * 512);
        *(float4*)&Ws[r * 516 + c] = *(const float4*)(src + c);
    }
    __syncthreads();

    const float4* h4 = (const float4*)(h + (size_t)b * 512);
    float acc = 0.f;
    #pragma unroll 8
    for (int i = 0; i < 128; ++i) {
        float4 a = h4[i];                               // 16-lane uniform -> merged
        float4 w = *(const float4*)&Ws[tx * 516 + i * 4];
        acc += a.x * w.x + a.y * w.y + a.z * w.z + a.w * w.w;
    }
    int n = n0 + tx;
    if (n < 2048) {
        float s = sigmoidf_(acc + b_beta[n]);
        gc[(size_t)b * 2048 + n] = s * context[(size_t)b * 2048 + n];
    } else {
        P0[(size_t)b * 2048 + (n - 2048)] = acc;
    }
}

// ---------------- step kernel 2: gates + fused LSTM ----------------
// grid (128, 4); block 256 thr = 16 cols x 16 b. Cols = 4 gates x 4 j's:
// tx -> g = tx>>2, dj = tx&3, G = g*512 + j0 + dj. K=2048 over gc (4 LDS chunks).
// Epilogue: v = acc + P0 + emb; shfl-gather 4 gates -> LSTM -> h, c, Hbf[(b*20+t)].
__global__ __launch_bounds__(256) void k_g2(
    const float* __restrict__ W_ih,
    const float* __restrict__ gc, const float* __restrict__ P0,
    const float* __restrict__ emb_t,
    float* __restrict__ h, float* __restrict__ cbuf,
    unsigned short* __restrict__ Hbf, int t) {
    const int tid = threadIdx.x;
    const int tx = tid & 15, ty = tid >> 4;
    const int j0 = blockIdx.x * 4;
    const int b  = blockIdx.y * 16 + ty;
    const int g  = tx >> 2, dj = tx & 3;
    const int G  = g * 512 + j0 + dj;

    __shared__ float Ws[16 * 516];

    // per-thread staging coords (row r holds W_ih row G(r) = (r>>2)*512 + j0 + (r&3))
    int fr[8], fc[8]; const float* fsrc[8];
    #pragma unroll
    for (int i = 0; i < 8; ++i) {
        int f = tid + i * 256;
        fr[i] = f >> 7; fc[i] = (f & 127) * 4;
        int Gr = (fr[i] >> 2) * 512 + j0 + (fr[i] & 3);
        fsrc[i] = W_ih + (size_t)Gr * 2560 + 512 + fc[i];
    }

    float4 pw[8];
    auto loadW = [&](int ch) {
        #pragma unroll
        for (int i = 0; i < 8; ++i)
            pw[i] = *(const float4*)(fsrc[i] + ch * 512);
    };

    const float4* gc4 = (const float4*)(gc + (size_t)b * 2048);
    float acc = 0.f;
    loadW(0);
    for (int ch = 0; ch < 4; ++ch) {
        __syncthreads();
        #pragma unroll
        for (int i = 0; i < 8; ++i)
            *(float4*)&Ws[fr[i] * 516 + fc[i]] = pw[i];
        __syncthreads();
        if (ch < 3) loadW(ch + 1);
        #pragma unroll 8
        for (int i = 0; i < 128; ++i) {
            float4 a = gc4[ch * 128 + i];
            float4 w = *(const float4*)&Ws[tx * 516 + i * 4];
            acc += a.x * w.x + a.y * w.y + a.z * w.z + a.w * w.w;
        }
    }

    float v = acc + P0[(size_t)b * 2048 + G] + emb_t[(size_t)b * 2048 + G];
    int lane = tid & 63;
    float vf = __shfl(v, lane + 4);
    float vg = __shfl(v, lane + 8);
    float vo = __shfl(v, lane + 12);
    if (g == 0) {
        int j = j0 + dj;
        float i_ = sigmoidf_(v);
        float f_ = sigmoidf_(vf);
        float g_ = tanhf(vg);
        float o_ = sigmoidf_(vo);
        size_t ci = (size_t)b * 512 + j;
        float cn = f_ * cbuf[ci] + i_ * g_;
        float hn = o_ * tanhf(cn);
        cbuf[ci] = cn;
        h[ci] = hn;
        Hbf[((size_t)b * Tt + t) * 512 + j] = bf16r(hn);
    }
}

// ---------------- W_out fp32 -> bf16 ----------------
__global__ __launch_bounds__(256) void k_cvt(const float* __restrict__ src,
                                             unsigned short* __restrict__ dst) {
    int i = blockIdx.x * 256 + threadIdx.x;
    if (i >= (Vv * Hh) / 4) return;
    float4 v = ((const float4*)src)[i];
    ushort4 o;
    o.x = bf16r(v.x); o.y = bf16r(v.y); o.z = bf16r(v.z); o.w = bf16r(v.w);
    ((ushort4*)dst)[i] = o;
}

// ---------------- preds: bf16 MFMA GEMM, 128x128 tile, BK=32 ----------------
// H rows in (b*20+t) order -> contiguous C writes.
__global__ __launch_bounds__(256) void gemm_preds(const unsigned short* __restrict__ Hb,
                                                  const unsigned short* __restrict__ Wb,
                                                  const float* __restrict__ b_out,
                                                  float* __restrict__ preds) {
    const int tid = threadIdx.x;
    const int lane = tid & 63, wave = tid >> 6;
    const int wr = wave >> 1, wc = wave & 1;
    const int m0 = blockIdx.x * 128, n0 = blockIdx.y * 128;

    __shared__ unsigned short As[128][40];
    __shared__ unsigned short Bs[128][40];

    const int r0 = tid >> 2, c8 = (tid & 3) * 8;
    uint4 pa[2], pb[2];
    auto load = [&](int c) {
        int k0 = c * 32;
        #pragma unroll
        for (int i = 0; i < 2; ++i) {
            int r = r0 + i * 64;
            pa[i] = *(const uint4*)(Hb + (size_t)(m0 + r) * 512 + k0 + c8);
            int gn = n0 + r; gn = (gn > Vv - 1) ? (Vv - 1) : gn;
            pb[i] = *(const uint4*)(Wb + (size_t)gn * 512 + k0 + c8);
        }
    };

    union F8 { bf16x8 v; struct { unsigned long long lo, hi; } u; };
    f32x4 acc[4][4] = {};

    const int arow = wr * 64 + (lane & 15);
    const int brow = wc * 64 + (lane & 15);
    const int kg = (lane >> 4) * 4;

    load(0);
    for (int c = 0; c < 16; ++c) {
        __syncthreads();
        #pragma unroll
        for (int i = 0; i < 2; ++i) {
            *(uint4*)&As[r0 + i * 64][c8] = pa[i];
            *(uint4*)&Bs[r0 + i * 64][c8] = pb[i];
        }
        __syncthreads();
        if (c < 15) load(c + 1);
        F8 af[4], bfr[4];
        #pragma unroll
        for (int x = 0; x < 4; ++x) {
            af[x].u.lo  = *(const unsigned long long*)&As[arow + x * 16][kg];
            af[x].u.hi  = *(const unsigned long long*)&As[arow + x * 16][16 + kg];
            bfr[x].u.lo = *(const unsigned long long*)&Bs[brow + x * 16][kg];
            bfr[x].u.hi = *(const unsigned long long*)&Bs[brow + x * 16][16 + kg];
        }
        #pragma unroll
        for (int mi = 0; mi < 4; ++mi)
            #pragma unroll
            for (int ni = 0; ni < 4; ++ni)
                acc[mi][ni] = __builtin_amdgcn_mfma_f32_16x16x32_bf16(
                    af[mi].v, bfr[ni].v, acc[mi][ni], 0, 0, 0);
    }

    const int crow = (lane >> 4) * 4, ccol = lane & 15;
    #pragma unroll
    for (int mi = 0; mi < 4; ++mi) {
        #pragma unroll
        for (int ni = 0; ni < 4; ++ni) {
            int n = n0 + wc * 64 + ni * 16 + ccol;
            if (n >= Vv) continue;
            float bo = b_out[n];
            #pragma unroll
            for (int r = 0; r < 4; ++r) {
                int m = m0 + wr * 64 + mi * 16 + crow + r;
                preds[(size_t)m * Vv + n] = acc[mi][ni][r] + bo;
            }
        }
    }
}

extern "C" void kernel_launch(void* const* d_in, const int* in_sizes, int n_in,
                              void* d_out, int out_size, void* d_ws, size_t ws_size,
                              hipStream_t stream) {
    const float* img_feat  = (const float*)d_in[0];
    const int*   captions  = (const int*)d_in[1];
    const float* embedding = (const float*)d_in[2];
    const float* W_enc_att = (const float*)d_in[3];
    const float* W_full    = (const float*)d_in[7];
    const float* W_beta    = (const float*)d_in[9];
    const float* b_beta    = (const float*)d_in[10];
    const float* W_ih      = (const float*)d_in[11];
    const float* b_ih      = (const float*)d_in[12];
    const float* W_hh      = (const float*)d_in[13];
    const float* b_hh      = (const float*)d_in[14];
    const float* W_init_h  = (const float*)d_in[15];
    const float* b_init_h  = (const float*)d_in[16];
    const float* W_init_c  = (const float*)d_in[17];
    const float* b_init_c  = (const float*)d_in[18];
    const float* W_out     = (const float*)d_in[19];
    const float* b_out     = (const float*)d_in[20];

    float* preds_out  = (float*)d_out;
    float* alphas_out = (float*)d_out + (size_t)Bsz * Tt * Vv;

    float* ws = (float*)d_ws;
    float* v_enc    = ws;                         // 2048
    float* sc       = v_enc + ENC;                // 12544
    float* alpha    = sc + Bsz * Pp;              // 12544
    float* context  = alpha + Bsz * Pp;           // 131072
    float* avg      = context + Bsz * ENC;        // 131072
    float* hbuf     = avg + Bsz * ENC;            // 32768
    float* cbuf     = hbuf + Bsz * Hh;            // 32768
    float* gc       = cbuf + Bsz * Hh;            // 131072
    float* P0       = gc + Bsz * ENC;             // 131072
    float* emb_part = P0 + Bsz * H4;              // 1280*2048
    unsigned short* H_bf16 = (unsigned short*)(emb_part + (size_t)Tt * Bsz * H4); // 1280*512
    unsigned short* Wout_bf16 = (unsigned short*)emb_part; // alias: used only after loop

    // attention (timestep-invariant)
    k_venc<<<32, 256, 0, stream>>>(W_full, W_enc_att, v_enc);
    k_scores<<<dim3(49, 64), 256, 0, stream>>>(img_feat, v_enc, sc);
    k_softmax<<<64, 256, 0, stream>>>(sc, alpha, alphas_out);
    k_ctx<<<dim3(4, 64), 256, 0, stream>>>(img_feat, alpha, context, avg);

    // h0 / c0 init
    gemm_init<<<64, 256, 0, stream>>>(
        avg, W_init_h, W_init_c, hbuf, cbuf, b_init_h, b_init_c);

    // embedding part of gates for all steps (gather fused; includes b_ih + b_hh)
    gemm_emb<<<dim3(H4 / 64, (Tt * Bsz) / 128), 256, 0, stream>>>(
        captions, embedding, W_ih, emb_part, b_ih, b_hh);

    // recurrence: 2 dispatches per step
    for (int t = 0; t < Tt; ++t) {
        k_g1<<<dim3(256, 4), 256, 0, stream>>>(
            W_beta, b_beta, W_hh, hbuf, context, gc, P0);
        k_g2<<<dim3(128, 4), 256, 0, stream>>>(
            W_ih, gc, P0, emb_part + (size_t)t * Bsz * H4,
            hbuf, cbuf, H_bf16, t);
    }

    // W_out -> bf16 (emb_part dead after loop)
    k_cvt<<<(Vv * Hh / 4 + 255) / 256, 256, 0, stream>>>(W_out, Wout_bf16);

    // preds via bf16 MFMA
    gemm_preds<<<dim3((Tt * Bsz) / 128, (Vv + 127) / 128), 256, 0, stream>>>(
        H_bf16, Wout_bf16, b_out, preds_out);
}